// Round 7
// baseline (23.697 us; speedup 1.0000x reference)
//
#include <hip/hip_runtime.h>

#define NBINS 256
#define NCH 3
#define NWAVES 4              // 256 threads / 64 lanes
#define BLOCK 256
#define HSIZE (NCH * NBINS)   // 768
#define BLOCKS_PER_BATCH 32
#define SUBS 24               // 24 sub-loads of 256 float4 each = 24576 floats/block

// Fully-coalesced variant: each wave-instruction reads 1KB contiguous (16 lines),
// channel bases precomputed per-thread and selected with compile-time indices.
template <bool USE_WS>
__global__ __launch_bounds__(BLOCK) void hist_kernel(const float* __restrict__ in,
                                                     unsigned int* __restrict__ ws,
                                                     float* __restrict__ out,
                                                     int floatsPerBatch,
                                                     float inv_n) {
    __shared__ unsigned int h[NWAVES][HSIZE];   // 12 KB

    const int tid = threadIdx.x;
    for (int i = tid; i < NWAVES * HSIZE; i += BLOCK) ((unsigned int*)h)[i] = 0u;
    __syncthreads();

    const int b     = blockIdx.x / BLOCKS_PER_BATCH;
    const int chunk = blockIdx.x % BLOCKS_PER_BATCH;
    const int chunkFloats = floatsPerBatch / BLOCKS_PER_BATCH;    // 24576
    const float4* p = (const float4*)(in + (size_t)b * floatsPerBatch
                                         + (size_t)chunk * chunkFloats) + tid;
    const int w = tid >> 6;

    // channel of element e of sub s for this thread = (tid + s + e) % 3
    // (baseElem % 3 == 0; 1024 % 3 == 1; 4 % 3 == 1). Precompute the 3 rotations.
    const int r = tid % 3;
    unsigned int cbase[3];
    cbase[0] = (unsigned int)(r << 8);
    cbase[1] = (unsigned int)(((r + 1 == 3) ? 0 : r + 1) << 8);
    cbase[2] = (unsigned int)(((r + 2 >= 3) ? r - 1 : r + 2) << 8);

#pragma unroll
    for (int it = 0; it < SUBS / 3; ++it) {
        float4 v0 = p[(it * 3 + 0) * BLOCK];
        float4 v1 = p[(it * 3 + 1) * BLOCK];
        float4 v2 = p[(it * 3 + 2) * BLOCK];
        const float vv[3][4] = {{v0.x, v0.y, v0.z, v0.w},
                                {v1.x, v1.y, v1.z, v1.w},
                                {v2.x, v2.y, v2.z, v2.w}};
#pragma unroll
        for (int k = 0; k < 3; ++k) {
            const int s = it * 3 + k;               // compile-time
#pragma unroll
            for (int e = 0; e < 4; ++e) {
                int bin = (int)(vv[k][e] * 256.0f); // v>=0: trunc == floor
                bin = bin < 0 ? 0 : (bin > NBINS - 1 ? NBINS - 1 : bin);
                const unsigned int cb = cbase[(s + e) % 3];   // compile-time index
                atomicAdd(&h[w][cb + bin], 1u);
            }
        }
    }
    __syncthreads();

    if (USE_WS) {
        // plain coalesced store of this block's partial histogram
        unsigned int* dst = ws + (size_t)blockIdx.x * HSIZE;
        for (int i = tid; i < HSIZE; i += BLOCK) {
            dst[i] = h[0][i] + h[1][i] + h[2][i] + h[3][i];
        }
    } else {
        // fallback: exact float atomics into transposed, pre-zeroed out
        float* dst = out + (size_t)b * HSIZE;
        for (int i = tid; i < HSIZE; i += BLOCK) {
            unsigned int sum = h[0][i] + h[1][i] + h[2][i] + h[3][i];
            if (sum) {
                const int c   = i >> 8;
                const int bin = i & (NBINS - 1);
                atomicAdd(&dst[bin * NCH + c], (float)sum * inv_n);
            }
        }
    }
}

// 32 blocks (one per batch) x 768 threads; tid = c*256 + bin.
__global__ __launch_bounds__(HSIZE) void reduce_kernel(const unsigned int* __restrict__ ws,
                                                       float* __restrict__ out,
                                                       float inv_n) {
    const int b = blockIdx.x;
    const int t = threadIdx.x;
    const unsigned int* p = ws + (size_t)b * BLOCKS_PER_BATCH * HSIZE + t;
    unsigned int s = 0;
#pragma unroll
    for (int ch = 0; ch < BLOCKS_PER_BATCH; ++ch) s += p[(size_t)ch * HSIZE];
    const int c   = t >> 8;
    const int bin = t & (NBINS - 1);
    out[(size_t)b * HSIZE + bin * NCH + c] = (float)s * inv_n;
}

extern "C" void kernel_launch(void* const* d_in, const int* in_sizes, int n_in,
                              void* d_out, int out_size, void* d_ws, size_t ws_size,
                              hipStream_t stream) {
    const float* in = (const float*)d_in[0];
    float* out = (float*)d_out;

    const int floatsPerBatch = 512 * 512 * 3;        // H*W*C
    const int total = in_sizes[0];
    const int B = total / floatsPerBatch;            // 32
    const float inv_n = 1.0f / (float)(512 * 512);   // 2^-18, exact

    const size_t wsNeeded = (size_t)B * BLOCKS_PER_BATCH * HSIZE * sizeof(unsigned int);

    if (ws_size >= wsNeeded) {
        unsigned int* ws = (unsigned int*)d_ws;
        hist_kernel<true><<<B * BLOCKS_PER_BATCH, BLOCK, 0, stream>>>(
            in, ws, out, floatsPerBatch, inv_n);
        reduce_kernel<<<B, HSIZE, 0, stream>>>(ws, out, inv_n);
    } else {
        hipMemsetAsync(d_out, 0, (size_t)out_size * sizeof(float), stream);
        hist_kernel<false><<<B * BLOCKS_PER_BATCH, BLOCK, 0, stream>>>(
            in, nullptr, out, floatsPerBatch, inv_n);
    }
}